// Round 7
// baseline (399.636 us; speedup 1.0000x reference)
//
#include <hip/hip_runtime.h>

// B=2, N=2048, DIM=1024, HEADS=16, DHEAD=64, INNER=1024. fp32 in/out.
// prep -> qkv GEMM (16x16x32, gld16, XOR-swizzle, XCD supertile) -> attn v11
// (= v10 + 32-key iter tiles: LDS 64->32KB -> 4 blocks/CU, 4 waves/SIMD so
// MFMA pipe and exp2/trans pipe overlap across waves; counted vmcnt(4)) ->
// out GEMM. similarity ignored: softmax row-const no-op.

typedef __attribute__((ext_vector_type(8))) short short8;
typedef __attribute__((ext_vector_type(4))) float float4_;
typedef __attribute__((ext_vector_type(16))) float floatx16;
typedef __attribute__((ext_vector_type(4))) unsigned short ushort4_;
typedef __attribute__((ext_vector_type(4))) unsigned int uint4_;

#define MFMA(a, b, c) __builtin_amdgcn_mfma_f32_16x16x32_bf16((a), (b), (c), 0, 0, 0)
#define MFMA32(a, b, c) __builtin_amdgcn_mfma_f32_32x32x16_bf16((a), (b), (c), 0, 0, 0)

static __device__ __forceinline__ unsigned short f2bf(float f) {
    union { float f; unsigned int u; } v; v.f = f;
    unsigned int r = v.u + 0x7FFFu + ((v.u >> 16) & 1u);  // RNE
    return (unsigned short)(r >> 16);
}

static __device__ __forceinline__ void gld16(const void* g, void* l) {
    __builtin_amdgcn_global_load_lds(
        (__attribute__((address_space(1))) void*)(g),
        (__attribute__((address_space(3))) void*)(l), 16, 0, 0);
}

// ---------------------------------------------------------------------------
// K0 prep: blocks 0..1023 transpose+convert weights; 1024..1535 convert X.
// ---------------------------------------------------------------------------
__global__ __launch_bounds__(256) void prep(
    const float* __restrict__ X, const float* __restrict__ Wq,
    const float* __restrict__ Wkv, const float* __restrict__ Wo,
    unsigned short* __restrict__ xb, unsigned short* __restrict__ Wt,
    unsigned short* __restrict__ Wot)
{
    const int bid = blockIdx.x, t = threadIdx.x;
    if (bid >= 1024) {
        const int b = bid - 1024;
        const float4_* src = (const float4_*)X;
        ushort4_* dst = (ushort4_*)xb;
        #pragma unroll
        for (int g = 0; g < 8; ++g) {
            const int idx = b * 2048 + g * 256 + t;
            float4_ v = src[idx];
            ushort4_ o;
            o[0] = f2bf(v[0]); o[1] = f2bf(v[1]);
            o[2] = f2bf(v[2]); o[3] = f2bf(v[3]);
            dst[idx] = o;
        }
        return;
    }
    __shared__ float tile[64][65];
    const float* src; unsigned short* dst; int N, kt, nt, drow0;
    if (bid < 256)      { src = Wq;  N = 1024; kt = bid & 15;       nt = bid >> 4;       dst = Wt;  drow0 = nt * 64; }
    else if (bid < 768) { src = Wkv; N = 2048; kt = (bid-256) & 15; nt = (bid-256) >> 4; dst = Wt;  drow0 = 1024 + nt * 64; }
    else                { src = Wo;  N = 1024; kt = (bid-768) & 15; nt = (bid-768) >> 4; dst = Wot; drow0 = nt * 64; }
    const int k0 = kt * 64, n0 = nt * 64;
    const int r0 = t >> 6, c = t & 63;
    #pragma unroll
    for (int i = 0; i < 16; ++i) {
        const int r = i * 4 + r0;
        tile[r][c] = src[(size_t)(k0 + r) * N + n0 + c];
    }
    __syncthreads();
    #pragma unroll
    for (int i = 0; i < 16; ++i) {
        const int rn = i * 4 + r0;
        dst[(size_t)(drow0 + rn) * 1024 + k0 + c] = f2bf(tile[c][rn]);
    }
}

// ---------------------------------------------------------------------------
// K1: QKV = xb @ Wt^T. 128x128 tile, gld16 + XOR swizzle. XCD supertile.
// Q row-major (scaled), K row-major, V^T [d][key].
// ---------------------------------------------------------------------------
__global__ __launch_bounds__(256) void qkv_gemm2(
    const unsigned short* __restrict__ xb, const unsigned short* __restrict__ Wt,
    unsigned short* __restrict__ q_ws, unsigned short* __restrict__ k_ws,
    unsigned short* __restrict__ vt_ws)
{
    __shared__ unsigned short As[128 * 64];
    __shared__ unsigned short Bs[128 * 64];
    const int t = threadIdx.x, wave = t >> 6, lane = t & 63;
    const int L = lane & 15, quad = lane >> 4;
    const int xcd = blockIdx.x & 7, idx = blockIdx.x >> 3;
    const int mb = (xcd >> 1) * 8 + (idx & 7);
    const int nb = (xcd & 1) * 12 + (idx >> 3);
    const int m0 = mb * 128, n0 = nb * 128;
    const int wr = wave >> 1, wc = wave & 1;

    float4_ z = {0.f, 0.f, 0.f, 0.f};
    float4_ acc[4][4];
    #pragma unroll
    for (int i = 0; i < 4; ++i)
        #pragma unroll
        for (int j = 0; j < 4; ++j) acc[i][j] = z;

    const unsigned short* gA[4]; const unsigned short* gB[4];
    unsigned short* lA[4]; unsigned short* lB[4];
    #pragma unroll
    for (int j = 0; j < 4; ++j) {
        const int cid = wave * 256 + j * 64 + lane;
        const int row = cid >> 3, pc = cid & 7;
        const int lch = pc ^ (row & 7);
        gA[j] = xb + (size_t)(m0 + row) * 1024 + lch * 8;
        gB[j] = Wt + (size_t)(n0 + row) * 1024 + lch * 8;
        lA[j] = As + wave * 2048 + j * 512;
        lB[j] = Bs + wave * 2048 + j * 512;
    }

    for (int kc = 0; kc < 1024; kc += 64) {
        #pragma unroll
        for (int j = 0; j < 4; ++j) {
            gld16(gA[j] + kc, lA[j]);
            gld16(gB[j] + kc, lB[j]);
        }
        __syncthreads();
        #pragma unroll
        for (int ks = 0; ks < 2; ++ks) {
            short8 af[4], bfr[4];
            #pragma unroll
            for (int mt = 0; mt < 4; ++mt) {
                const int rl = wr * 64 + mt * 16 + L;
                af[mt] = *(const short8*)(As + rl * 64 + (((ks * 4 + quad) ^ (L & 7)) << 3));
            }
            #pragma unroll
            for (int nt = 0; nt < 4; ++nt) {
                const int rl = wc * 64 + nt * 16 + L;
                bfr[nt] = *(const short8*)(Bs + rl * 64 + (((ks * 4 + quad) ^ (L & 7)) << 3));
            }
            #pragma unroll
            for (int mt = 0; mt < 4; ++mt)
                #pragma unroll
                for (int nt = 0; nt < 4; ++nt)
                    acc[mt][nt] = MFMA(af[mt], bfr[nt], acc[mt][nt]);
        }
        __syncthreads();
    }

    const int b = m0 >> 11;
    const int type = n0 >> 10;  // 0=Q, 1=K, 2=V
    #pragma unroll
    for (int mt = 0; mt < 4; ++mt) {
        const int m = (m0 & 2047) + wr * 64 + mt * 16 + quad * 4;
        #pragma unroll
        for (int nt = 0; nt < 4; ++nt) {
            const int cl = (n0 & 1023) + wc * 64 + nt * 16 + L;
            const int h = cl >> 6, d = cl & 63;
            float4_ v = acc[mt][nt];
            if (type == 0) {
                // fold 0.125 softmax scale and log2(e): exp(x)=exp2(x*log2e)
                unsigned short* p = q_ws + ((size_t)(b * 16 + h) * 2048 + m) * 64 + d;
                #pragma unroll
                for (int r = 0; r < 4; ++r) p[(size_t)r * 64] = f2bf(v[r] * 0.18033688011f);
            } else if (type == 1) {
                unsigned short* p = k_ws + ((size_t)(b * 16 + h) * 2048 + m) * 64 + d;
                #pragma unroll
                for (int r = 0; r < 4; ++r) p[(size_t)r * 64] = f2bf(v[r]);
            } else {
                ushort4_ pk;
                pk[0] = f2bf(v[0]); pk[1] = f2bf(v[1]);
                pk[2] = f2bf(v[2]); pk[3] = f2bf(v[3]);
                *(ushort4_*)(vt_ws + ((size_t)(b * 16 + h) * 64 + d) * 2048 + m) = pk;
            }
        }
    }
}

// ---------------------------------------------------------------------------
// K2 v11: 32-key iter tiles for occupancy. 512 blocks x 256 threads = 4
// waves (qg x kh). LDS 33KB -> 4 blocks/CU -> 4 waves/SIMD: MFMA and exp2
// overlap across waves. K tile [32 key-rows][64 d] (128B rows, same pi +
// 3-bit XOR as v10). V tile [32 rows][2 d-halves x 32 keys] (128B rows,
// 2-bit key-chunk XOR, both-sides). 32 iters, counted vmcnt(4).
// ---------------------------------------------------------------------------
#define WAITV4 asm volatile("s_waitcnt vmcnt(4)" ::: "memory")
#define WAITV0 asm volatile("s_waitcnt vmcnt(0)" ::: "memory")
#define WAITL0 asm volatile("s_waitcnt lgkmcnt(0)" ::: "memory")
#define BAR    __builtin_amdgcn_s_barrier()

__global__ __launch_bounds__(256, 4) void attn_fwd11(
    const unsigned short* __restrict__ q_ws,
    const unsigned short* __restrict__ k_ws,
    const unsigned short* __restrict__ vt_ws,
    unsigned short* __restrict__ o2)
{
    // pool: K [kh][buf][2048 sh] @ 0..8191; V [kh][buf][2048 sh] @ 8192..16383
    __shared__ unsigned short pool[16384];   // 32 KB
    __shared__ float lsd[2][2][2][32];       // [kh][qg][qt][l32]
    const int t = threadIdx.x, wave = t >> 6, lane = t & 63;
    const int l32 = lane & 31, hi = lane >> 5;
    const int qg = wave & 1, kh = wave >> 1;
    const int xcd = blockIdx.x & 7, loc = blockIdx.x >> 3;
    const int bh = xcd * 4 + (loc >> 4);
    const int qb = loc & 15;

    const unsigned short* Kp = k_ws + (size_t)bh * 2048 * 64;
    const unsigned short* Vt = vt_ws + (size_t)bh * 64 * 2048;

    // Q fragments: 64 q-rows per wave (qt=2), 8 short8.
    short8 qf[2][4];
    #pragma unroll
    for (int qt = 0; qt < 2; ++qt) {
        const unsigned short* Qp = q_ws
            + ((size_t)(bh * 2048 + qb * 128 + qg * 64 + qt * 32 + l32)) * 64 + hi * 8;
        #pragma unroll
        for (int k = 0; k < 4; ++k) qf[qt][k] = *(const short8*)(Qp + k * 16);
    }
    WAITV0;  // drain Q loads so in-loop vmcnt arithmetic is exact

    // Staging: per wave 2 K-chunks + 2 V-chunks (1KB each). The two qg waves
    // of a kh group together cover each 4KB tile.
    const unsigned short* kg[2]; const unsigned short* vg[2];
    unsigned short* kdst[2]; unsigned short* vdst[2];
    #pragma unroll
    for (int g = 0; g < 2; ++g) {
        const int cid = g * 128 + qg * 64 + lane;
        // K: row kr in 0..31 (keys), chunk = d-chunk, 3-bit XOR, pi rows.
        const int kr = cid >> 3;
        const int kl = (cid & 7) ^ (kr & 7);
        const int pr = (kr & ~12) | ((kr & 4) << 1) | ((kr & 8) >> 1);  // pi
        kg[g] = Kp + (size_t)(kh * 1024 + pr) * 64 + kl * 8;
        // V: row r holds d=r (chunks 0..3) and d=r+32 (chunks 4..7);
        // key-chunk = (p&3)^(r&3) (2-bit XOR, matched on read).
        const int vr = cid >> 3, vp = cid & 7;
        const int vd = vr + 32 * (vp >> 2);
        const int vkc = (vp & 3) ^ (vr & 3);
        vg[g] = Vt + (size_t)vd * 2048 + kh * 1024 + vkc * 8;
        kdst[g] = pool + kh * 4096 + g * 1024 + qg * 512;
        vdst[g] = pool + 8192 + kh * 4096 + g * 1024 + qg * 512;
    }

#define STAGE11(p_, it_) do {                                                 \
    const int ko_ = (it_) * 2048; /* 32 key-rows * 64 d */                    \
    const int vo_ = (it_) * 32;   /* 32 keys along V rows */                  \
    _Pragma("unroll")                                                         \
    for (int g = 0; g < 2; ++g) gld16(kg[g] + ko_, kdst[g] + (p_) * 2048);    \
    _Pragma("unroll")                                                         \
    for (int g = 0; g < 2; ++g) gld16(vg[g] + vo_, vdst[g] + (p_) * 2048);    \
} while (0)

    floatx16 o00, o01, o10, o11;
    #pragma unroll
    for (int r = 0; r < 16; ++r) { o00[r] = 0.f; o01[r] = 0.f; o10[r] = 0.f; o11[r] = 0.f; }
    float lsum0 = 0.f, lsum1 = 0.f;

    STAGE11(0, 0);
    const int sw = l32 & 7;
    const int sw2 = l32 & 3;

    #pragma unroll 1
    for (int it = 0; it < 32; ++it) {
        const int p = it & 1;
        if (it + 1 < 32) { STAGE11(p ^ 1, it + 1); WAITV4; }
        else             { WAITV0; }
        BAR;

        const unsigned short* kb = pool + kh * 4096 + p * 2048;
        const unsigned short* vb = pool + 8192 + kh * 4096 + p * 2048;

        // QK^T over 32 keys: one key-block, 2 qt.
        floatx16 s00, s10;
        #pragma unroll
        for (int r = 0; r < 16; ++r) { s00[r] = 0.f; s10[r] = 0.f; }
        #pragma unroll
        for (int k = 0; k < 4; ++k) {
            const int off = (((2 * k + hi) ^ sw) << 3);
            short8 k0 = *(const short8*)(kb + l32 * 64 + off);
            s00 = MFMA32(k0, qf[0][k], s00);
            s10 = MFMA32(k0, qf[1][k], s10);
        }

        // exp2 + byte-pack (verbatim v5 pattern, single key-block per qt).
        unsigned int pkA[8], pkB[8];
        #pragma unroll
        for (int d = 0; d < 8; ++d) {
            union { float f; unsigned int u; } a0, b0, a1, b1;
            a0.f = __builtin_amdgcn_exp2f(s00[2 * d]);
            b0.f = __builtin_amdgcn_exp2f(s00[2 * d + 1]);
            a1.f = __builtin_amdgcn_exp2f(s10[2 * d]);
            b1.f = __builtin_amdgcn_exp2f(s10[2 * d + 1]);
            lsum0 += a0.f + b0.f;
            lsum1 += a1.f + b1.f;
            pkA[d] = __builtin_amdgcn_perm(b0.u, a0.u, 0x07060302u);
            pkB[d] = __builtin_amdgcn_perm(b1.u, a1.u, 0x07060302u);
        }

        // PV: w in {0,1}; V key-chunk c = 2w+hi in 0..3; d-halves via +32.
        #pragma unroll
        for (int w = 0; w < 2; ++w) {
            const int c = 2 * w + hi;
            const int voff = ((c ^ sw2) << 3);
            short8 vf0 = *(const short8*)(vb + l32 * 64 + voff);        // d=l32
            short8 vf1 = *(const short8*)(vb + l32 * 64 + 32 + voff);   // d=l32+32
            uint4_ pwA, pwB;
            if (w == 0) { pwA[0]=pkA[0]; pwA[1]=pkA[1]; pwA[2]=pkA[2]; pwA[3]=pkA[3];
                          pwB[0]=pkB[0]; pwB[1]=pkB[1]; pwB[2]=pkB[2]; pwB[3]=pkB[3]; }
            else        { pwA[0]=pkA[4]; pwA[1]=pkA[5]; pwA[2]=pkA[6]; pwA[3]=pkA[7];
                          pwB[0]=pkB[4]; pwB[1]=pkB[5]; pwB[2]=pkB[6]; pwB[3]=pkB[7]; }
            short8 paA = *(short8*)&pwA;
            short8 paB = *(short8*)&pwB;
            o00 = MFMA32(paA, vf0, o00); o01 = MFMA32(paA, vf1, o01);
            o10 = MFMA32(paB, vf0, o10); o11 = MFMA32(paB, vf1, o11);
        }
        WAITL0;   // my reads of buffer p done
        BAR;      // all waves done reading -> next STAGE may overwrite p
    }

    const float lt0 = lsum0 + __shfl_xor(lsum0, 32);
    const float lt1 = lsum1 + __shfl_xor(lsum1, 32);
    lsd[kh][qg][0][l32] = lt0;
    lsd[kh][qg][1][l32] = lt1;

    // kh=1 waves donate O-partials via LDS (aliases pool; safe after final
    // barrier). kh=0 waves add, normalize, store. 2 qg x 4096 f32 = 32 KB.
    float* cb = (float*)pool;
    if (kh == 1) {
        float* base = cb + qg * 4096;
        #pragma unroll
        for (int r = 0; r < 16; ++r) {
            base[(0 * 16 + r) * 64 + lane] = o00[r];
            base[(1 * 16 + r) * 64 + lane] = o01[r];
            base[(2 * 16 + r) * 64 + lane] = o10[r];
            base[(3 * 16 + r) * 64 + lane] = o11[r];
        }
    }
    __syncthreads();
    if (kh == 0) {
        const int b = bh >> 4, h = bh & 15;
        const float* base = cb + qg * 4096;
        unsigned short* obase = o2
            + ((size_t)(b * 2048 + qb * 128 + qg * 64)) * 1024 + h * 64;
        #pragma unroll
        for (int r = 0; r < 16; ++r) {
            const int rowloc = (r & 3) + 8 * (r >> 2) + 4 * hi;
            const float i0 = 1.0f / (lsd[0][qg][0][rowloc] + lsd[1][qg][0][rowloc]);
            const float i1 = 1.0f / (lsd[0][qg][1][rowloc] + lsd[1][qg][1][rowloc]);
            const float a0 = o00[r] + base[(0 * 16 + r) * 64 + lane];
            const float a1 = o01[r] + base[(1 * 16 + r) * 64 + lane];
            const float b0 = o10[r] + base[(2 * 16 + r) * 64 + lane];
            const float b1 = o11[r] + base[(3 * 16 + r) * 64 + lane];
            obase[(size_t)rowloc * 1024 + l32]             = f2bf(a0 * i0);
            obase[(size_t)rowloc * 1024 + 32 + l32]        = f2bf(a1 * i0);
            obase[(size_t)(32 + rowloc) * 1024 + l32]      = f2bf(b0 * i1);
            obase[(size_t)(32 + rowloc) * 1024 + 32 + l32] = f2bf(b1 * i1);
        }
    }
#undef STAGE11
}

// ---------------------------------------------------------------------------
// K3: Out = o2 @ Wot^T + bo (fp32 out). 128x64 tile. XCD supertile.
// ---------------------------------------------------------------------------
__global__ __launch_bounds__(256) void out_gemm2(
    const unsigned short* __restrict__ o2, const unsigned short* __restrict__ Wot,
    const float* __restrict__ bo, float* __restrict__ Out)
{
    __shared__ unsigned short As[128 * 64];
    __shared__ unsigned short Bs[64 * 64];
    const int t = threadIdx.x, wave = t >> 6, lane = t & 63;
    const int L = lane & 15, quad = lane >> 4;
    const int xcd = blockIdx.x & 7, idx = blockIdx.x >> 3;
    const int mb = (xcd >> 1) * 8 + (idx & 7);
    const int nb = (xcd & 1) * 8 + (idx >> 3);
    const int m0 = mb * 128, n0 = nb * 64;
    const int wr = wave >> 1, wc = wave & 1;

    float4_ z = {0.f, 0.f, 0.f, 0.f};
    float4_ acc[4][2];
    #pragma unroll
    for (int i = 0; i < 4; ++i)
        #pragma unroll
        for (int j = 0; j < 2; ++j) acc[i][j] = z;

    const unsigned short* gA[4]; unsigned short* lA[4];
    #pragma unroll
    for (int j = 0; j < 4; ++j) {
        const int cid = wave * 256 + j * 64 + lane;
        const int row = cid >> 3, pc = cid & 7;
        gA[j] = o2 + (size_t)(m0 + row) * 1024 + (pc ^ (row & 7)) * 8;
        lA[j] = As + wave * 2048 + j * 512;
    }
    const unsigned short* gB[2]; unsigned short* lB[2];
    #pragma unroll
    for (int j = 0; j < 2; ++j) {
        const int cid = wave * 128 + j * 64 + lane;
        const int row = cid >> 3, pc = cid & 7;
        gB[j] = Wot + (size_t)(n0 + row) * 1024 + (pc ^ (row & 7)) * 8;
        lB[j] = Bs + wave * 1024 + j * 512;
    }

    for (int kc = 0; kc < 1024; kc += 64) {
        #pragma unroll
        for (int j = 0; j < 4; ++j) gld16(gA[j] + kc, lA[j]);
        #pragma unroll
        for (int j = 0; j < 2; ++j) gld16(gB[j] + kc, lB[j]);
        __syncthreads();
        #pragma unroll
        for (int ks = 0; ks < 2; ++ks) {
            short8 af[4], bfr[2];
            #pragma unroll
            for (int mt = 0; mt < 4; ++mt) {
                const int rl = wr * 64 + mt * 16 + L;
                af[mt] = *(const short8*)(As + rl * 64 + (((ks * 4 + quad) ^ (L & 7)) << 3));
            }
            #pragma unroll
            for (int nt = 0; nt < 2; ++nt) {
                const int rl = wc * 32 + nt * 16 + L;
                bfr[nt] = *(const short8*)(Bs + rl * 64 + (((ks * 4 + quad) ^ (L & 7)) << 3));
            }
            #pragma unroll
            for (int mt = 0; mt < 4; ++mt)
                #pragma unroll
                for (int nt = 0; nt < 2; ++nt)
                    acc[mt][nt] = MFMA(af[mt], bfr[nt], acc[mt][nt]);
        }
        __syncthreads();
    }

    #pragma unroll
    for (int mt = 0; mt < 4; ++mt) {
        const int m = m0 + wr * 64 + mt * 16 + quad * 4;
        #pragma unroll
        for (int nt = 0; nt < 2; ++nt) {
            const int c = n0 + wc * 32 + nt * 16 + L;
            const float bias = bo[c];
            #pragma unroll
            for (int r = 0; r < 4; ++r)
                Out[(size_t)(m + r) * 1024 + c] = acc[mt][nt][r] + bias;
        }
    }
}

// ---------------------------------------------------------------------------
extern "C" void kernel_launch(void* const* d_in, const int* in_sizes, int n_in,
                              void* d_out, int out_size, void* d_ws, size_t ws_size,
                              hipStream_t stream) {
    const float* x   = (const float*)d_in[0];
    // d_in[1] = similarity: softmax no-op, ignored.
    const float* Wq  = (const float*)d_in[2];
    const float* Wkv = (const float*)d_in[3];
    const float* Wo  = (const float*)d_in[4];
    const float* bo  = (const float*)d_in[5];
    float* out = (float*)d_out;

    char* ws = (char*)d_ws;
    const size_t MB = 1024 * 1024;
    unsigned short* xb   = (unsigned short*)(ws);            // 8 MB; reused as o2
    unsigned short* o2   = xb;                               // alias (xb dead after K1)
    unsigned short* Wt   = (unsigned short*)(ws + 8 * MB);   // 6 MB
    unsigned short* Wot  = (unsigned short*)(ws + 14 * MB);  // 2 MB
    unsigned short* q_ws = (unsigned short*)(ws + 16 * MB);  // 8 MB
    unsigned short* k_ws = (unsigned short*)(ws + 24 * MB);  // 8 MB (row-major)
    unsigned short* vt_ws= (unsigned short*)(ws + 32 * MB);  // 8 MB ([d][key])

    prep<<<dim3(1536), dim3(256), 0, stream>>>(x, Wq, Wkv, Wo, xb, Wt, Wot);
    qkv_gemm2<<<dim3(768), dim3(256), 0, stream>>>(xb, Wt, q_ws, k_ws, vt_ws);
    attn_fwd11<<<dim3(512), dim3(256), 0, stream>>>(q_ws, k_ws, vt_ws, o2);
    out_gemm2<<<dim3(512), dim3(256), 0, stream>>>(o2, Wot, bo, out);
}

// Round 8
// 189.004 us; speedup vs baseline: 2.1144x; 2.1144x over previous
//
#include <hip/hip_runtime.h>

// B=2, N=2048, DIM=1024, HEADS=16, DHEAD=64, INNER=1024. fp32 in/out.
// prep -> qkv GEMM (16x16x32, gld16, XOR-swizzle, XCD supertile) -> attn v12
// (4 waves/SIMD for real: v11's 32-key tiles/33KB LDS + qt=1 so per-wave
// state ~105 regs fits the 128-reg cap that v11 blew; 1024 blocks = 4/CU
// fully resident; counted vmcnt(4)) -> out GEMM. similarity ignored.

typedef __attribute__((ext_vector_type(8))) short short8;
typedef __attribute__((ext_vector_type(4))) float float4_;
typedef __attribute__((ext_vector_type(16))) float floatx16;
typedef __attribute__((ext_vector_type(4))) unsigned short ushort4_;
typedef __attribute__((ext_vector_type(4))) unsigned int uint4_;

#define MFMA(a, b, c) __builtin_amdgcn_mfma_f32_16x16x32_bf16((a), (b), (c), 0, 0, 0)
#define MFMA32(a, b, c) __builtin_amdgcn_mfma_f32_32x32x16_bf16((a), (b), (c), 0, 0, 0)

static __device__ __forceinline__ unsigned short f2bf(float f) {
    union { float f; unsigned int u; } v; v.f = f;
    unsigned int r = v.u + 0x7FFFu + ((v.u >> 16) & 1u);  // RNE
    return (unsigned short)(r >> 16);
}

static __device__ __forceinline__ void gld16(const void* g, void* l) {
    __builtin_amdgcn_global_load_lds(
        (__attribute__((address_space(1))) void*)(g),
        (__attribute__((address_space(3))) void*)(l), 16, 0, 0);
}

// ---------------------------------------------------------------------------
// K0 prep: blocks 0..1023 transpose+convert weights; 1024..1535 convert X.
// ---------------------------------------------------------------------------
__global__ __launch_bounds__(256) void prep(
    const float* __restrict__ X, const float* __restrict__ Wq,
    const float* __restrict__ Wkv, const float* __restrict__ Wo,
    unsigned short* __restrict__ xb, unsigned short* __restrict__ Wt,
    unsigned short* __restrict__ Wot)
{
    const int bid = blockIdx.x, t = threadIdx.x;
    if (bid >= 1024) {
        const int b = bid - 1024;
        const float4_* src = (const float4_*)X;
        ushort4_* dst = (ushort4_*)xb;
        #pragma unroll
        for (int g = 0; g < 8; ++g) {
            const int idx = b * 2048 + g * 256 + t;
            float4_ v = src[idx];
            ushort4_ o;
            o[0] = f2bf(v[0]); o[1] = f2bf(v[1]);
            o[2] = f2bf(v[2]); o[3] = f2bf(v[3]);
            dst[idx] = o;
        }
        return;
    }
    __shared__ float tile[64][65];
    const float* src; unsigned short* dst; int N, kt, nt, drow0;
    if (bid < 256)      { src = Wq;  N = 1024; kt = bid & 15;       nt = bid >> 4;       dst = Wt;  drow0 = nt * 64; }
    else if (bid < 768) { src = Wkv; N = 2048; kt = (bid-256) & 15; nt = (bid-256) >> 4; dst = Wt;  drow0 = 1024 + nt * 64; }
    else                { src = Wo;  N = 1024; kt = (bid-768) & 15; nt = (bid-768) >> 4; dst = Wot; drow0 = nt * 64; }
    const int k0 = kt * 64, n0 = nt * 64;
    const int r0 = t >> 6, c = t & 63;
    #pragma unroll
    for (int i = 0; i < 16; ++i) {
        const int r = i * 4 + r0;
        tile[r][c] = src[(size_t)(k0 + r) * N + n0 + c];
    }
    __syncthreads();
    #pragma unroll
    for (int i = 0; i < 16; ++i) {
        const int rn = i * 4 + r0;
        dst[(size_t)(drow0 + rn) * 1024 + k0 + c] = f2bf(tile[c][rn]);
    }
}

// ---------------------------------------------------------------------------
// K1: QKV = xb @ Wt^T. 128x128 tile, gld16 + XOR swizzle. XCD supertile.
// Q row-major (scaled), K row-major, V^T [d][key].
// ---------------------------------------------------------------------------
__global__ __launch_bounds__(256) void qkv_gemm2(
    const unsigned short* __restrict__ xb, const unsigned short* __restrict__ Wt,
    unsigned short* __restrict__ q_ws, unsigned short* __restrict__ k_ws,
    unsigned short* __restrict__ vt_ws)
{
    __shared__ unsigned short As[128 * 64];
    __shared__ unsigned short Bs[128 * 64];
    const int t = threadIdx.x, wave = t >> 6, lane = t & 63;
    const int L = lane & 15, quad = lane >> 4;
    const int xcd = blockIdx.x & 7, idx = blockIdx.x >> 3;
    const int mb = (xcd >> 1) * 8 + (idx & 7);
    const int nb = (xcd & 1) * 12 + (idx >> 3);
    const int m0 = mb * 128, n0 = nb * 128;
    const int wr = wave >> 1, wc = wave & 1;

    float4_ z = {0.f, 0.f, 0.f, 0.f};
    float4_ acc[4][4];
    #pragma unroll
    for (int i = 0; i < 4; ++i)
        #pragma unroll
        for (int j = 0; j < 4; ++j) acc[i][j] = z;

    const unsigned short* gA[4]; const unsigned short* gB[4];
    unsigned short* lA[4]; unsigned short* lB[4];
    #pragma unroll
    for (int j = 0; j < 4; ++j) {
        const int cid = wave * 256 + j * 64 + lane;
        const int row = cid >> 3, pc = cid & 7;
        const int lch = pc ^ (row & 7);
        gA[j] = xb + (size_t)(m0 + row) * 1024 + lch * 8;
        gB[j] = Wt + (size_t)(n0 + row) * 1024 + lch * 8;
        lA[j] = As + wave * 2048 + j * 512;
        lB[j] = Bs + wave * 2048 + j * 512;
    }

    for (int kc = 0; kc < 1024; kc += 64) {
        #pragma unroll
        for (int j = 0; j < 4; ++j) {
            gld16(gA[j] + kc, lA[j]);
            gld16(gB[j] + kc, lB[j]);
        }
        __syncthreads();
        #pragma unroll
        for (int ks = 0; ks < 2; ++ks) {
            short8 af[4], bfr[4];
            #pragma unroll
            for (int mt = 0; mt < 4; ++mt) {
                const int rl = wr * 64 + mt * 16 + L;
                af[mt] = *(const short8*)(As + rl * 64 + (((ks * 4 + quad) ^ (L & 7)) << 3));
            }
            #pragma unroll
            for (int nt = 0; nt < 4; ++nt) {
                const int rl = wc * 64 + nt * 16 + L;
                bfr[nt] = *(const short8*)(Bs + rl * 64 + (((ks * 4 + quad) ^ (L & 7)) << 3));
            }
            #pragma unroll
            for (int mt = 0; mt < 4; ++mt)
                #pragma unroll
                for (int nt = 0; nt < 4; ++nt)
                    acc[mt][nt] = MFMA(af[mt], bfr[nt], acc[mt][nt]);
        }
        __syncthreads();
    }

    const int b = m0 >> 11;
    const int type = n0 >> 10;  // 0=Q, 1=K, 2=V
    #pragma unroll
    for (int mt = 0; mt < 4; ++mt) {
        const int m = (m0 & 2047) + wr * 64 + mt * 16 + quad * 4;
        #pragma unroll
        for (int nt = 0; nt < 4; ++nt) {
            const int cl = (n0 & 1023) + wc * 64 + nt * 16 + L;
            const int h = cl >> 6, d = cl & 63;
            float4_ v = acc[mt][nt];
            if (type == 0) {
                // fold 0.125 softmax scale and log2(e): exp(x)=exp2(x*log2e)
                unsigned short* p = q_ws + ((size_t)(b * 16 + h) * 2048 + m) * 64 + d;
                #pragma unroll
                for (int r = 0; r < 4; ++r) p[(size_t)r * 64] = f2bf(v[r] * 0.18033688011f);
            } else if (type == 1) {
                unsigned short* p = k_ws + ((size_t)(b * 16 + h) * 2048 + m) * 64 + d;
                #pragma unroll
                for (int r = 0; r < 4; ++r) p[(size_t)r * 64] = f2bf(v[r]);
            } else {
                ushort4_ pk;
                pk[0] = f2bf(v[0]); pk[1] = f2bf(v[1]);
                pk[2] = f2bf(v[2]); pk[3] = f2bf(v[3]);
                *(ushort4_*)(vt_ws + ((size_t)(b * 16 + h) * 64 + d) * 2048 + m) = pk;
            }
        }
    }
}

// ---------------------------------------------------------------------------
// K2 v12: qt=1 + 32-key tiles -> true 4 waves/SIMD. 1024 blocks x 256
// threads (4/CU fully resident). Block = (bh, 64 q-rows); wave = (qg, kh):
// 32 q-rows x 1024 keys each, 32 iters of 32 keys. Per-wave state ~105 regs
// (o 32 + qf 16 + s 16 + pk 8 + addr) fits the 128 unified cap. LDS 33 KB.
// K tile: v10 pi+3-bit-XOR layout (32 rows). V tile: v11 [32 rows][2 d-half
// x 32 keys] 2-bit-XOR layout (verified R7). Counted vmcnt(4).
// ---------------------------------------------------------------------------
#define WAITV4 asm volatile("s_waitcnt vmcnt(4)" ::: "memory")
#define WAITV0 asm volatile("s_waitcnt vmcnt(0)" ::: "memory")
#define WAITL0 asm volatile("s_waitcnt lgkmcnt(0)" ::: "memory")
#define BAR    __builtin_amdgcn_s_barrier()

__global__ __launch_bounds__(256, 4) void attn_fwd12(
    const unsigned short* __restrict__ q_ws,
    const unsigned short* __restrict__ k_ws,
    const unsigned short* __restrict__ vt_ws,
    unsigned short* __restrict__ o2)
{
    // pool: K [kh][buf][2048 sh] @ 0..8191; V [kh][buf][2048 sh] @ 8192..16383
    __shared__ unsigned short pool[16384];   // 32 KB
    __shared__ float lsd[2][2][32];          // [kh][qg][l32]
    const int t = threadIdx.x, wave = t >> 6, lane = t & 63;
    const int l32 = lane & 31, hi = lane >> 5;
    const int qg = wave & 1, kh = wave >> 1;
    const int xcd = blockIdx.x & 7, loc = blockIdx.x >> 3;
    const int bh = xcd * 4 + (loc >> 5);
    const int qb = loc & 31;   // 64-row q tile per block

    const unsigned short* Kp = k_ws + (size_t)bh * 2048 * 64;
    const unsigned short* Vt = vt_ws + (size_t)bh * 64 * 2048;

    // Q fragments: 32 q-rows per wave (qt=1), 4 short8 = 16 regs.
    short8 qf[4];
    {
        const unsigned short* Qp = q_ws
            + ((size_t)(bh * 2048 + qb * 64 + qg * 32 + l32)) * 64 + hi * 8;
        #pragma unroll
        for (int k = 0; k < 4; ++k) qf[k] = *(const short8*)(Qp + k * 16);
    }
    WAITV0;  // drain Q loads so in-loop vmcnt arithmetic is exact

    // Staging (v11 verbatim): per wave 2 K-chunks + 2 V-chunks (1KB each);
    // the two qg waves of a kh group together cover each 4KB tile.
    const unsigned short* kg[2]; const unsigned short* vg[2];
    unsigned short* kdst[2]; unsigned short* vdst[2];
    #pragma unroll
    for (int g = 0; g < 2; ++g) {
        const int cid = g * 128 + qg * 64 + lane;
        const int kr = cid >> 3;
        const int kl = (cid & 7) ^ (kr & 7);
        const int pr = (kr & ~12) | ((kr & 4) << 1) | ((kr & 8) >> 1);  // pi
        kg[g] = Kp + (size_t)(kh * 1024 + pr) * 64 + kl * 8;
        const int vr = cid >> 3, vp = cid & 7;
        const int vd = vr + 32 * (vp >> 2);
        const int vkc = (vp & 3) ^ (vr & 3);
        vg[g] = Vt + (size_t)vd * 2048 + kh * 1024 + vkc * 8;
        kdst[g] = pool + kh * 4096 + g * 1024 + qg * 512;
        vdst[g] = pool + 8192 + kh * 4096 + g * 1024 + qg * 512;
    }

#define STAGE12(p_, it_) do {                                                 \
    const int ko_ = (it_) * 2048; /* 32 key-rows * 64 d */                    \
    const int vo_ = (it_) * 32;   /* 32 keys along V rows */                  \
    _Pragma("unroll")                                                         \
    for (int g = 0; g < 2; ++g) gld16(kg[g] + ko_, kdst[g] + (p_) * 2048);    \
    _Pragma("unroll")                                                         \
    for (int g = 0; g < 2; ++g) gld16(vg[g] + vo_, vdst[g] + (p_) * 2048);    \
} while (0)

    floatx16 o0, o1;
    #pragma unroll
    for (int r = 0; r < 16; ++r) { o0[r] = 0.f; o1[r] = 0.f; }
    float lsum = 0.f;

    STAGE12(0, 0);
    const int sw = l32 & 7;
    const int sw2 = l32 & 3;

    #pragma unroll 1
    for (int it = 0; it < 32; ++it) {
        const int p = it & 1;
        if (it + 1 < 32) { STAGE12(p ^ 1, it + 1); WAITV4; }
        else             { WAITV0; }
        BAR;

        const unsigned short* kb = pool + kh * 4096 + p * 2048;
        const unsigned short* vb = pool + 8192 + kh * 4096 + p * 2048;

        // QK^T over 32 keys, 32 q-rows.
        floatx16 s;
        #pragma unroll
        for (int r = 0; r < 16; ++r) s[r] = 0.f;
        #pragma unroll
        for (int k = 0; k < 4; ++k) {
            const int off = (((2 * k + hi) ^ sw) << 3);
            short8 k0 = *(const short8*)(kb + l32 * 64 + off);
            s = MFMA32(k0, qf[k], s);
        }

        // exp2 + byte-pack (verbatim pattern).
        unsigned int pk[8];
        #pragma unroll
        for (int d = 0; d < 8; ++d) {
            union { float f; unsigned int u; } a0, b0;
            a0.f = __builtin_amdgcn_exp2f(s[2 * d]);
            b0.f = __builtin_amdgcn_exp2f(s[2 * d + 1]);
            lsum += a0.f + b0.f;
            pk[d] = __builtin_amdgcn_perm(b0.u, a0.u, 0x07060302u);
        }

        // PV: w in {0,1}; V key-chunk c = 2w+hi in 0..3; d-halves via +32.
        #pragma unroll
        for (int w = 0; w < 2; ++w) {
            const int c = 2 * w + hi;
            const int voff = ((c ^ sw2) << 3);
            short8 vf0 = *(const short8*)(vb + l32 * 64 + voff);        // d=l32
            short8 vf1 = *(const short8*)(vb + l32 * 64 + 32 + voff);   // d=l32+32
            uint4_ pw;
            if (w == 0) { pw[0] = pk[0]; pw[1] = pk[1]; pw[2] = pk[2]; pw[3] = pk[3]; }
            else        { pw[0] = pk[4]; pw[1] = pk[5]; pw[2] = pk[6]; pw[3] = pk[7]; }
            short8 pa = *(short8*)&pw;
            o0 = MFMA32(pa, vf0, o0);
            o1 = MFMA32(pa, vf1, o1);
        }
        WAITL0;   // my reads of buffer p done
        BAR;      // all waves done reading -> next STAGE may overwrite p
    }

    // Row-sum totals over this wave's 1024 keys (both key-row halves).
    const float lt = lsum + __shfl_xor(lsum, 32);
    lsd[kh][qg][l32] = lt;

    // kh=1 donates O-partials via LDS (aliases pool; safe after final
    // barrier). kh=0 adds, normalizes, stores. 2 qg x 2048 f32 = 16 KB.
    float* cb = (float*)pool;
    if (kh == 1) {
        float* base = cb + qg * 2048;
        #pragma unroll
        for (int r = 0; r < 16; ++r) {
            base[r * 64 + lane]        = o0[r];
            base[(16 + r) * 64 + lane] = o1[r];
        }
    }
    __syncthreads();
    if (kh == 0) {
        const int b = bh >> 4, h = bh & 15;
        const float* base = cb + qg * 2048;
        unsigned short* obase = o2
            + ((size_t)(b * 2048 + qb * 64 + qg * 32)) * 1024 + h * 64;
        #pragma unroll
        for (int r = 0; r < 16; ++r) {
            const int rowloc = (r & 3) + 8 * (r >> 2) + 4 * hi;
            const float iv = 1.0f / (lsd[0][qg][rowloc] + lsd[1][qg][rowloc]);
            const float a0 = o0[r] + base[r * 64 + lane];
            const float a1 = o1[r] + base[(16 + r) * 64 + lane];
            obase[(size_t)rowloc * 1024 + l32]      = f2bf(a0 * iv);
            obase[(size_t)rowloc * 1024 + 32 + l32] = f2bf(a1 * iv);
        }
    }
#undef STAGE12
}

// ---------------------------------------------------------------------------
// K3: Out = o2 @ Wot^T + bo (fp32 out). 128x64 tile. XCD supertile.
// ---------------------------------------------------------------------------
__global__ __launch_bounds__(256) void out_gemm2(
    const unsigned short* __restrict__ o2, const unsigned short* __restrict__ Wot,
    const float* __restrict__ bo, float* __restrict__ Out)
{
    __shared__ unsigned short As[128 * 64];
    __shared__ unsigned short Bs[64 * 64];
    const int t = threadIdx.x, wave = t >> 6, lane = t & 63;
    const int L = lane & 15, quad = lane >> 4;
    const int xcd = blockIdx.x & 7, idx = blockIdx.x >> 3;
    const int mb = (xcd >> 1) * 8 + (idx & 7);
    const int nb = (xcd & 1) * 8 + (idx >> 3);
    const int m0 = mb * 128, n0 = nb * 64;
    const int wr = wave >> 1, wc = wave & 1;

    float4_ z = {0.f, 0.f, 0.f, 0.f};
    float4_ acc[4][2];
    #pragma unroll
    for (int i = 0; i < 4; ++i)
        #pragma unroll
        for (int j = 0; j < 2; ++j) acc[i][j] = z;

    const unsigned short* gA[4]; unsigned short* lA[4];
    #pragma unroll
    for (int j = 0; j < 4; ++j) {
        const int cid = wave * 256 + j * 64 + lane;
        const int row = cid >> 3, pc = cid & 7;
        gA[j] = o2 + (size_t)(m0 + row) * 1024 + (pc ^ (row & 7)) * 8;
        lA[j] = As + wave * 2048 + j * 512;
    }
    const unsigned short* gB[2]; unsigned short* lB[2];
    #pragma unroll
    for (int j = 0; j < 2; ++j) {
        const int cid = wave * 128 + j * 64 + lane;
        const int row = cid >> 3, pc = cid & 7;
        gB[j] = Wot + (size_t)(n0 + row) * 1024 + (pc ^ (row & 7)) * 8;
        lB[j] = Bs + wave * 1024 + j * 512;
    }

    for (int kc = 0; kc < 1024; kc += 64) {
        #pragma unroll
        for (int j = 0; j < 4; ++j) gld16(gA[j] + kc, lA[j]);
        #pragma unroll
        for (int j = 0; j < 2; ++j) gld16(gB[j] + kc, lB[j]);
        __syncthreads();
        #pragma unroll
        for (int ks = 0; ks < 2; ++ks) {
            short8 af[4], bfr[2];
            #pragma unroll
            for (int mt = 0; mt < 4; ++mt) {
                const int rl = wr * 64 + mt * 16 + L;
                af[mt] = *(const short8*)(As + rl * 64 + (((ks * 4 + quad) ^ (L & 7)) << 3));
            }
            #pragma unroll
            for (int nt = 0; nt < 2; ++nt) {
                const int rl = wc * 32 + nt * 16 + L;
                bfr[nt] = *(const short8*)(Bs + rl * 64 + (((ks * 4 + quad) ^ (L & 7)) << 3));
            }
            #pragma unroll
            for (int mt = 0; mt < 4; ++mt)
                #pragma unroll
                for (int nt = 0; nt < 2; ++nt)
                    acc[mt][nt] = MFMA(af[mt], bfr[nt], acc[mt][nt]);
        }
        __syncthreads();
    }

    #pragma unroll
    for (int mt = 0; mt < 4; ++mt) {
        const int m = m0 + wr * 64 + mt * 16 + quad * 4;
        #pragma unroll
        for (int nt = 0; nt < 2; ++nt) {
            const int c = n0 + wc * 32 + nt * 16 + L;
            const float bias = bo[c];
            #pragma unroll
            for (int r = 0; r < 4; ++r)
                Out[(size_t)(m + r) * 1024 + c] = acc[mt][nt][r] + bias;
        }
    }
}

// ---------------------------------------------------------------------------
extern "C" void kernel_launch(void* const* d_in, const int* in_sizes, int n_in,
                              void* d_out, int out_size, void* d_ws, size_t ws_size,
                              hipStream_t stream) {
    const float* x   = (const float*)d_in[0];
    // d_in[1] = similarity: softmax no-op, ignored.
    const float* Wq  = (const float*)d_in[2];
    const float* Wkv = (const float*)d_in[3];
    const float* Wo  = (const float*)d_in[4];
    const float* bo  = (const float*)d_in[5];
    float* out = (float*)d_out;

    char* ws = (char*)d_ws;
    const size_t MB = 1024 * 1024;
    unsigned short* xb   = (unsigned short*)(ws);            // 8 MB; reused as o2
    unsigned short* o2   = xb;                               // alias (xb dead after K1)
    unsigned short* Wt   = (unsigned short*)(ws + 8 * MB);   // 6 MB
    unsigned short* Wot  = (unsigned short*)(ws + 14 * MB);  // 2 MB
    unsigned short* q_ws = (unsigned short*)(ws + 16 * MB);  // 8 MB
    unsigned short* k_ws = (unsigned short*)(ws + 24 * MB);  // 8 MB (row-major)
    unsigned short* vt_ws= (unsigned short*)(ws + 32 * MB);  // 8 MB ([d][key])

    prep<<<dim3(1536), dim3(256), 0, stream>>>(x, Wq, Wkv, Wo, xb, Wt, Wot);
    qkv_gemm2<<<dim3(768), dim3(256), 0, stream>>>(xb, Wt, q_ws, k_ws, vt_ws);
    attn_fwd12<<<dim3(1024), dim3(256), 0, stream>>>(q_ws, k_ws, vt_ws, o2);
    out_gemm2<<<dim3(512), dim3(256), 0, stream>>>(o2, Wot, bo, out);
}